// Round 10
// baseline (3361.428 us; speedup 1.0000x reference)
//
#include <hip/hip_runtime.h>

#define TT 2048

typedef _Float16 f16;
typedef _Float16 f16x2 __attribute__((ext_vector_type(2)));
typedef _Float16 f16x8 __attribute__((ext_vector_type(8)));
typedef float f32x4 __attribute__((ext_vector_type(4)));
typedef unsigned int u32;

static __device__ __forceinline__ u32 packh2(float a, float b) {
  f16x2 v; v[0] = (f16)a; v[1] = (f16)b;
  return __builtin_bit_cast(u32, v);
}
static __device__ __forceinline__ uint4 pack8(float4 a, float4 b) {
  uint4 r;
  r.x = packh2(a.x, a.y); r.y = packh2(a.z, a.w);
  r.z = packh2(b.x, b.y); r.w = packh2(b.z, b.w);
  return r;
}
static __device__ __forceinline__ float sigm(float x) {
  return 1.f / (1.f + __expf(-x));
}
static __device__ __forceinline__ float tanh_(float x) {
  x = fminf(15.f, fmaxf(-15.f, x));
  const float e = __expf(2.f * x);
  return (e - 1.f) / (e + 1.f);
}
static __device__ __forceinline__ f16x8 ldfrag16(const f16* p) {
  return __builtin_bit_cast(f16x8, *(const uint4*)p);
}
static __device__ __forceinline__ f32x4 MF(f16x8 a, f16x8 b, f32x4 c) {
  return __builtin_amdgcn_mfma_f32_16x16x32_f16(a, b, c, 0, 0, 0);
}

// ============ prep kernel: weights -> f16 fragment layout in d_ws ============
// Fragment tile T (0..87), lane L (0..63): 8 f16 at wsf[T*512 + L*8].
//  T<64: L1 wave w=T>>4, fi=T&15: fi<8 -> Wih1, else Whh1; q=(fi&7)>>1, c=fi&1;
//        row = 64q+16w+(L&15), k0 = 32c + (L>>4)*8, ld=64.
//  T>=64: L2 w2=(T-64)/12, fi=(T-64)%12: fi<8 -> Wih2 (q=fi>>1,c=fi&1,ld=64);
//        fi>=8 -> Whh2 (q=fi-8, ld=32, k0=(L>>4)*8); row = 32q+16w2+(L&15).
// Block 88: biases -> wsb[384] (L1: (4w+q)*16+ln; L2: 256+(4w2+q)*16+ln).
__global__ void lstm2_prep_kernel(const float* __restrict__ Wih1,
                                  const float* __restrict__ Whh1,
                                  const float* __restrict__ Wih2,
                                  const float* __restrict__ Whh2,
                                  const float* __restrict__ bih1,
                                  const float* __restrict__ bhh1,
                                  const float* __restrict__ bih2,
                                  const float* __restrict__ bhh2,
                                  f16* __restrict__ wsf,
                                  float* __restrict__ wsb)
{
  const int T = blockIdx.x;
  const int L = threadIdx.x;
  if (T < 88) {
    const int ln = L & 15, lg = L >> 4;
    const float* src; int row, ld, k0;
    if (T < 64) {
      const int w = T >> 4, fi = T & 15;
      const int q = (fi & 7) >> 1, c = fi & 1;
      row = 64 * q + 16 * w + ln; ld = 64; k0 = 32 * c + lg * 8;
      src = (fi < 8) ? Wih1 : Whh1;
    } else {
      const int t2 = T - 64, w2 = t2 / 12, fi = t2 % 12;
      if (fi < 8) {
        const int q = fi >> 1, c = fi & 1;
        row = 32 * q + 16 * w2 + ln; ld = 64; k0 = 32 * c + lg * 8; src = Wih2;
      } else {
        const int q = fi - 8;
        row = 32 * q + 16 * w2 + ln; ld = 32; k0 = lg * 8; src = Whh2;
      }
    }
    #pragma unroll
    for (int j = 0; j < 8; ++j)
      wsf[T * 512 + L * 8 + j] = (f16)src[row * ld + k0 + j];
  } else {
    for (int idx = L; idx < 384; idx += 64) {
      float b;
      if (idx < 256) {
        const int grp = idx >> 4, ln = idx & 15;
        const int w = grp >> 2, q = grp & 3;
        const int g = 64 * q + 16 * w + ln;
        b = bih1[g] + bhh1[g];
      } else {
        const int v = idx - 256, grp = v >> 4, ln = v & 15;
        const int w2 = grp >> 2, q = grp & 3;
        const int g = 32 * q + 16 * w2 + ln;
        b = bih2[g] + bhh2[g];
      }
      wsb[idx] = b;
    }
  }
}

// ============ main kernel: MFMA persistent LSTM, packed-counter flags ========
__launch_bounds__(448, 1)
__global__ void lstm2_main_kernel(const float* __restrict__ x1,
                                  const float* __restrict__ x2,
                                  const f16* __restrict__ wsf,
                                  const float* __restrict__ wsb,
                                  float* __restrict__ out)
{
  __shared__ __align__(16) u32 s_ring[16][512];   // x ring, slot = t & 15
  __shared__ __align__(16) f16 s_h1[4][16][72];   // h1 ring, slot = t & 3
  __shared__ __align__(16) f16 s_h2[4][16][40];   // h2 ring, slot = t & 3
  __shared__ int s_c1;   // sum of L1 wave step-completions (4 per step)
  __shared__ int s_c2;   // sum of L2 wave step-completions (2 per step)
  __shared__ int s_fx;   // x steps staged

  const int tid = threadIdx.x;
  const int l = tid & 63;
  const int wid = tid >> 6;        // 0-3 L1, 4-5 L2, 6 x-stage
  const int ln = l & 15;
  const int lg = l >> 4;
  const int bid = blockIdx.x;      // 32 blocks
  const int which = bid >> 4;
  const int rowbase = (bid & 15) * 16;

  for (int idx = tid; idx < 16 * 72; idx += 448) ((f16*)s_h1[3])[idx] = (f16)0.f;
  for (int idx = tid; idx < 16 * 40; idx += 448) ((f16*)s_h2[3])[idx] = (f16)0.f;
  if (tid == 0) { s_c1 = 0; s_c2 = 0; s_fx = 8; }

  const float* __restrict__ xrow =
      (which ? x2 : x1) + (size_t)(rowbase + ln) * (TT * 64);

  // ---- stager prologue: steps 0..7 into ring slots 0..7 ----
  if (wid == 6) {
    #pragma unroll 1
    for (int p = 0; p < 8; ++p) {
      const float* ps = xrow + p * 64;
      const float4 a0 = *(const float4*)(ps + lg * 8);
      const float4 a1 = *(const float4*)(ps + lg * 8 + 4);
      const float4 b0 = *(const float4*)(ps + 32 + lg * 8);
      const float4 b1 = *(const float4*)(ps + 32 + lg * 8 + 4);
      *(uint4*)&s_ring[p][lg * 64 + ln * 4] = pack8(a0, a1);
      *(uint4*)&s_ring[p][256 + lg * 64 + ln * 4] = pack8(b0, b1);
    }
  }
  __syncthreads();   // the ONLY barrier

  volatile int* vc1 = (volatile int*)&s_c1;
  volatile int* vc2 = (volatile int*)&s_c2;
  volatile int* vfx = (volatile int*)&s_fx;

  if (wid < 4) {
    // ================= layer-1 serial waves =================
    const f16* wp = wsf + (size_t)(wid * 16) * 512 + l * 8;
    const f16x8 wx0 = ldfrag16(wp +  0 * 512), wx1 = ldfrag16(wp +  1 * 512);
    const f16x8 wx2 = ldfrag16(wp +  2 * 512), wx3 = ldfrag16(wp +  3 * 512);
    const f16x8 wx4 = ldfrag16(wp +  4 * 512), wx5 = ldfrag16(wp +  5 * 512);
    const f16x8 wx6 = ldfrag16(wp +  6 * 512), wx7 = ldfrag16(wp +  7 * 512);
    const f16x8 wh0 = ldfrag16(wp +  8 * 512), wh1 = ldfrag16(wp +  9 * 512);
    const f16x8 wh2 = ldfrag16(wp + 10 * 512), wh3 = ldfrag16(wp + 11 * 512);
    const f16x8 wh4 = ldfrag16(wp + 12 * 512), wh5 = ldfrag16(wp + 13 * 512);
    const f16x8 wh6 = ldfrag16(wp + 14 * 512), wh7 = ldfrag16(wp + 15 * 512);
    const float bs0 = wsb[(wid * 4 + 0) * 16 + ln];
    const float bs1 = wsb[(wid * 4 + 1) * 16 + ln];
    const float bs2 = wsb[(wid * 4 + 2) * 16 + ln];
    const float bs3 = wsb[(wid * 4 + 3) * 16 + ln];
    const int uu = 16 * wid + ln;
    float cc[4] = {0.f, 0.f, 0.f, 0.f};
    const f32x4 z4 = {0.f, 0.f, 0.f, 0.f};

    #pragma unroll 1
    for (int i = 0; i < TT; ++i) {
      while (*vfx < i + 1) { }
      const u32* rs = s_ring[i & 15];
      const f16x8 xa0 = *(const f16x8*)&rs[lg * 64 + ln * 4];
      const f16x8 xa1 = *(const f16x8*)&rs[256 + lg * 64 + ln * 4];
      // two parallel accumulation chains per gate (halve MFMA dep depth)
      f32x4 a0 = {bs0, bs0, bs0, bs0}, e0 = z4;
      f32x4 a1 = {bs1, bs1, bs1, bs1}, e1 = z4;
      f32x4 a2 = {bs2, bs2, bs2, bs2}, e2 = z4;
      f32x4 a3 = {bs3, bs3, bs3, bs3}, e3 = z4;
      a0 = MF(xa0, wx0, a0); e0 = MF(xa1, wx1, e0);
      a1 = MF(xa0, wx2, a1); e1 = MF(xa1, wx3, e1);
      a2 = MF(xa0, wx4, a2); e2 = MF(xa1, wx5, e2);
      a3 = MF(xa0, wx6, a3); e3 = MF(xa1, wx7, e3);
      // wait for all four peers to have finished step i-1
      while (*vc1 < 4 * i) { }
      const f16* hb = &s_h1[(i - 1) & 3][ln][lg * 8];
      const f16x8 ha0 = *(const f16x8*)hb;
      const f16x8 ha1 = *(const f16x8*)(hb + 32);
      a0 = MF(ha0, wh0, a0); e0 = MF(ha1, wh1, e0);
      a1 = MF(ha0, wh2, a1); e1 = MF(ha1, wh3, e1);
      a2 = MF(ha0, wh4, a2); e2 = MF(ha1, wh5, e2);
      a3 = MF(ha0, wh6, a3); e3 = MF(ha1, wh7, e3);
      a0 += e0; a1 += e1; a2 += e2; a3 += e3;
      // back-pressure: slot i&3 held h1[i-4]; L2 must be past step i-4
      while (*vc2 < 2 * (i - 3)) { }
      #pragma unroll
      for (int r2 = 0; r2 < 4; ++r2) {
        const float gi = sigm(a0[r2]), gf = sigm(a1[r2]);
        const float gg = tanh_(a2[r2]), go = sigm(a3[r2]);
        cc[r2] = gf * cc[r2] + gi * gg;
        const float hv = go * tanh_(cc[r2]);
        s_h1[i & 3][lg * 4 + r2][uu] = (f16)hv;
      }
      asm volatile("s_waitcnt lgkmcnt(0)" ::: "memory");
      if (l == 0) atomicAdd(&s_c1, 1);
    }
  } else if (wid < 6) {
    // ================= layer-2 waves (one step behind) =================
    const int w2 = wid - 4;
    const f16* wp = wsf + (size_t)(64 + w2 * 12) * 512 + l * 8;
    const f16x8 wx0 = ldfrag16(wp + 0 * 512), wx1 = ldfrag16(wp + 1 * 512);
    const f16x8 wx2 = ldfrag16(wp + 2 * 512), wx3 = ldfrag16(wp + 3 * 512);
    const f16x8 wx4 = ldfrag16(wp + 4 * 512), wx5 = ldfrag16(wp + 5 * 512);
    const f16x8 wx6 = ldfrag16(wp + 6 * 512), wx7 = ldfrag16(wp + 7 * 512);
    const f16x8 wg0 = ldfrag16(wp + 8 * 512), wg1 = ldfrag16(wp + 9 * 512);
    const f16x8 wg2 = ldfrag16(wp + 10 * 512), wg3 = ldfrag16(wp + 11 * 512);
    const float bs0 = wsb[256 + (w2 * 4 + 0) * 16 + ln];
    const float bs1 = wsb[256 + (w2 * 4 + 1) * 16 + ln];
    const float bs2 = wsb[256 + (w2 * 4 + 2) * 16 + ln];
    const float bs3 = wsb[256 + (w2 * 4 + 3) * 16 + ln];
    const int uu = 16 * w2 + ln;
    float cc[4] = {0.f, 0.f, 0.f, 0.f};
    const f32x4 z4 = {0.f, 0.f, 0.f, 0.f};

    #pragma unroll 1
    for (int t = 0; t < TT; ++t) {
      while (*vc1 < 4 * (t + 1)) { }
      while (*vc2 < 2 * t) { }
      const f16* hb = &s_h1[t & 3][ln][lg * 8];
      const f16x8 ha0 = *(const f16x8*)hb;
      const f16x8 ha1 = *(const f16x8*)(hb + 32);
      const f16x8 g0 = *(const f16x8*)&s_h2[(t - 1) & 3][ln][lg * 8];
      f32x4 b0 = {bs0, bs0, bs0, bs0}, e0 = z4;
      f32x4 b1 = {bs1, bs1, bs1, bs1}, e1 = z4;
      f32x4 b2 = {bs2, bs2, bs2, bs2}, e2 = z4;
      f32x4 b3 = {bs3, bs3, bs3, bs3}, e3 = z4;
      b0 = MF(ha0, wx0, b0); e0 = MF(ha1, wx1, e0);
      b1 = MF(ha0, wx2, b1); e1 = MF(ha1, wx3, e1);
      b2 = MF(ha0, wx4, b2); e2 = MF(ha1, wx5, e2);
      b3 = MF(ha0, wx6, b3); e3 = MF(ha1, wx7, e3);
      b0 = MF(g0, wg0, b0); b1 = MF(g0, wg1, b1);
      b2 = MF(g0, wg2, b2); b3 = MF(g0, wg3, b3);
      b0 += e0; b1 += e1; b2 += e2; b3 += e3;
      #pragma unroll
      for (int r2 = 0; r2 < 4; ++r2) {
        const float gi = sigm(b0[r2]), gf = sigm(b1[r2]);
        const float gg = tanh_(b2[r2]), go = sigm(b3[r2]);
        cc[r2] = gf * cc[r2] + gi * gg;
        const float hv = go * tanh_(cc[r2]);
        s_h2[t & 3][lg * 4 + r2][uu] = (f16)hv;
        if (t == TT - 1)
          out[which * 8192 + (rowbase + lg * 4 + r2) * 32 + uu] = hv;
      }
      asm volatile("s_waitcnt lgkmcnt(0)" ::: "memory");
      if (l == 0) atomicAdd(&s_c2, 1);
    }
  } else {
    // ================= x stager =================
    #pragma unroll 1
    for (int s = 8; s < TT; s += 8) {
      while (*vc1 < 4 * (s - 8)) { }
      #pragma unroll
      for (int p = 0; p < 8; ++p) {
        const float* ps = xrow + (s + p) * 64;
        const float4 a0 = *(const float4*)(ps + lg * 8);
        const float4 a1 = *(const float4*)(ps + lg * 8 + 4);
        const float4 b0 = *(const float4*)(ps + 32 + lg * 8);
        const float4 b1 = *(const float4*)(ps + 32 + lg * 8 + 4);
        u32* rd = s_ring[(s + p) & 15];
        *(uint4*)&rd[lg * 64 + ln * 4] = pack8(a0, a1);
        *(uint4*)&rd[256 + lg * 64 + ln * 4] = pack8(b0, b1);
      }
      asm volatile("s_waitcnt lgkmcnt(0)" ::: "memory");
      if (l == 0) *vfx = s + 8;
    }
  }
}

extern "C" void kernel_launch(void* const* d_in, const int* in_sizes, int n_in,
                              void* d_out, int out_size, void* d_ws, size_t ws_size,
                              hipStream_t stream) {
  const float* x1   = (const float*)d_in[0];
  const float* x2   = (const float*)d_in[1];
  const float* Wih1 = (const float*)d_in[2];
  const float* Whh1 = (const float*)d_in[3];
  const float* bih1 = (const float*)d_in[4];
  const float* bhh1 = (const float*)d_in[5];
  const float* Wih2 = (const float*)d_in[6];
  const float* Whh2 = (const float*)d_in[7];
  const float* bih2 = (const float*)d_in[8];
  const float* bhh2 = (const float*)d_in[9];
  float* out = (float*)d_out;

  f16*   wsf = (f16*)d_ws;                       // 88 KiB fragment region
  float* wsb = (float*)((char*)d_ws + 88 * 1024); // 384 f32 biases

  lstm2_prep_kernel<<<dim3(89), dim3(64), 0, stream>>>(
      Wih1, Whh1, Wih2, Whh2, bih1, bhh1, bih2, bhh2, wsf, wsb);
  lstm2_main_kernel<<<dim3(32), dim3(448), 0, stream>>>(
      x1, x2, wsf, wsb, out);
}